// Round 6
// baseline (18.623 us; speedup 1.0000x reference)
//
#include <hip/hip_runtime.h>

// Euler characteristic curve of sublevel cubical complex.
// x: [B,C,H,W] f32 -> out: [B,C,RES] f32.
//
// Single hist kernel, per (image, row-slice) block:
//   - per-vertex contribution = two telescoping bin-pairs
//       {+1 @ b(v), -1 @ b(v|right)}  and  {-1 @ b(v|down), +1 @ b(face)}
//     (bin is monotone: bin(max(a,b)) == max(bin(a),bin(b)));
//     pairs whose bins coincide are net no-ops -> branch-skipped so those
//     lanes are exec-masked out of the ds_add (≈ halves LDS atomic lane-work).
//   - right-halo bin via __shfl(u0, lane+1) (boundary lanes masked) ->
//     1 float4 load per 4 vertices, no scalar halo loads.
//   - hist[bin][lane] int32 LDS (16 KiB), ds_add fire-and-forget.
//   - epilogue: block reduces its 64 lane-columns, 64-lane shfl inclusive
//     scan (cumsum is linear => per-slice cumsum ok), float atomicAdd to out
//     (integer-valued => exact & order-independent). out zeroed by memset node.

#define BB 32
#define CC 16
#define HH 128
#define WW 128
#define RESB 64
#define NT 256
#define S 4
#define ROWS (HH / S)    // 32 rows per slice
#define RPT (ROWS / 8)   // 4 consecutive rows per thread
#define BC (BB * CC)

__device__ __forceinline__ int binq(float F) {
    // F in [0,1): ceil(F*63) already lands in [0,63] -- no clamps needed.
    return (int)ceilf(F * 63.0f);
}

__global__ __launch_bounds__(NT, 8) void ecc_hist(const float* __restrict__ X,
                                                  float* __restrict__ out) {
    __shared__ int hist[RESB * 64];  // [bin][lane], 16 KiB
    const int blk = blockIdx.x;
    const int sl = blk & (S - 1);
    const int bc = blk >> 2;  // blk / S
    const int tid = threadIdx.x;
    const int lane = tid & 63;
    const float* __restrict__ x = X + (size_t)bc * (HH * WW);

    {
        int4* h4 = (int4*)hist;
#pragma unroll
        for (int k = 0; k < 4; ++k) h4[k * NT + tid] = make_int4(0, 0, 0, 0);
    }
    __syncthreads();

    const int col4 = tid & 31;   // which float4 of the row
    const int tr = tid >> 5;     // 0..7 thread-row group
    const int r0 = sl * ROWS + tr * RPT;
    const int c0 = col4 * 4;
    const int nxt = (lane + 1) & 63;  // right-neighbor lane (wrap lanes masked)

    int u[5], v[5];
    {
        const float4 a = *(const float4*)(x + r0 * WW + c0);
        u[0] = binq(a.x); u[1] = binq(a.y); u[2] = binq(a.z); u[3] = binq(a.w);
        u[4] = __shfl(u[0], nxt, 64);
    }

#pragma unroll
    for (int dr = 0; dr < RPT; ++dr) {
        const int r = r0 + dr;
        const int hD = (r < HH - 1) ? 1 : 0;
        const int r1 = hD ? r + 1 : r;  // last image row: dup (contribs masked)
        {
            const float4 b = *(const float4*)(x + r1 * WW + c0);
            v[0] = binq(b.x); v[1] = binq(b.y); v[2] = binq(b.z); v[3] = binq(b.w);
            v[4] = __shfl(v[0], nxt, 64);
        }
#pragma unroll
        for (int k = 0; k < 4; ++k) {
            const int hR = (k < 3) ? 1 : ((col4 < 31) ? 1 : 0);  // folds for k<3
            const int u00 = u[k];
            const int bh  = max(u00, u[k + 1]);
            const int bvv = max(u00, v[k]);
            const int bf  = max(bh, max(v[k], v[k + 1]));
            // pair A: vertex + h-edge (telescoping)
            if (hR) {
                if (bh != u00) {
                    atomicAdd(&hist[u00 * 64 + lane], 1);
                    atomicAdd(&hist[bh * 64 + lane], -1);
                }
            } else {
                atomicAdd(&hist[u00 * 64 + lane], 1);
            }
            // pair B: v-edge + face (telescoping)
            if (hD) {
                if (hR) {
                    if (bf != bvv) {
                        atomicAdd(&hist[bvv * 64 + lane], -1);
                        atomicAdd(&hist[bf * 64 + lane], 1);
                    }
                } else {
                    atomicAdd(&hist[bvv * 64 + lane], -1);
                }
            }
        }
#pragma unroll
        for (int k = 0; k < 5; ++k) u[k] = v[k];
    }
    __syncthreads();

    // Reduce over 64 lane-columns: thread (bin = tid&63, q = tid>>6) sums 16.
    const int bin = tid & 63;
    const int q = tid >> 6;
    int ssum = 0;
#pragma unroll
    for (int k = 0; k < 16; ++k) {
        ssum += hist[bin * 64 + q * 16 + ((k + bin) & 15)];
    }
    __syncthreads();
    hist[tid] = ssum;  // partial at [q*64 + bin]
    __syncthreads();
    if (tid < RESB) {
        int vv = hist[tid] + hist[tid + 64] + hist[tid + 128] + hist[tid + 192];
        // Inclusive prefix scan across 64 lanes (= bins): per-slice cumsum.
#pragma unroll
        for (int d = 1; d < 64; d <<= 1) {
            const int up = __shfl_up(vv, d, 64);
            if (tid >= d) vv += up;
        }
        atomicAdd(&out[bc * RESB + tid], (float)vv);  // exact: integer-valued
    }
}

extern "C" void kernel_launch(void* const* d_in, const int* in_sizes, int n_in,
                              void* d_out, int out_size, void* d_ws, size_t ws_size,
                              hipStream_t stream) {
    const float* x = (const float*)d_in[0];
    float* out = (float*)d_out;
    hipMemsetAsync(out, 0, (size_t)BC * RESB * sizeof(float), stream);
    ecc_hist<<<BC * S, NT, 0, stream>>>(x, out);
}